// Round 5
// baseline (18291.664 us; speedup 1.0000x reference)
//
#include <hip/hip_runtime.h>
#include <cstdint>
#include <cstddef>

// Problem constants
#define T_STEPS 8192
#define IN_DIM  1024
#define HID     1024
#define OUT_DIM 1024
#define G4      4096   // 4*HID

// Recurrence geometry: 256 blocks x 256 threads (4 waves), 1 block/CU.
// R13: step = 3400cy but post-detect compute is only ~300-400cy -- the rest
// is communication. Theory: the poll SWEEPS themselves saturate L3 (2MB of
// line-reads into 128 hot lines per sweep, from 1024 desynced waves),
// inflating both detect latency and publish visibility. (Retro-explains
// R10: 2x poll traffic -> 17.5ms, super-linear.)
// FIX: masked retry -- tags are monotonic and final once matched, so each
// of the 4 poll loads is predicated on its own per-lane !ok flag. Lanes
// that have their entry stop issuing transactions; steady-state poll
// traffic drops ~3-5x. Everything else byte-identical to R12 (11.62ms).
#define NBLK 256
#define TPB  256
#define UPB  4    // units per block (1 per wave)

typedef __attribute__((ext_vector_type(4))) float f32x4;

#define PLOAD(p) __hip_atomic_load((p), __ATOMIC_RELAXED, __HIP_MEMORY_SCOPE_AGENT)

__device__ __forceinline__ float sigf(float x) {
  return 1.0f / (1.0f + __expf(-x));
}

template<int CTRL>
__device__ __forceinline__ float dpp_add(float v) {
  int p = __builtin_amdgcn_update_dpp(0, __float_as_int(v), CTRL, 0xf, 0xf, true);
  return v + __int_as_float(p);
}

// Full 64-lane sum, all-VALU (DPP). Result valid in LANE 63 only.
__device__ __forceinline__ float wave_sum63(float v) {
  v = dpp_add<0xB1>(v);    // quad_perm [1,0,3,2]
  v = dpp_add<0x4E>(v);    // quad_perm [2,3,0,1]
  v = dpp_add<0x141>(v);   // row_half_mirror
  v = dpp_add<0x140>(v);   // row_mirror
  v = dpp_add<0x142>(v);   // row_bcast15
  v = dpp_add<0x143>(v);   // row_bcast31
  return v;
}

// ---------------------------------------------------------------------------
// Fused persistent LSTM: tagged dataflow (no device barrier), LDS-resident
// W_h and W_x, reg-resident out_w row. hbuf: [2][1024] u64 {lo=tag, hi=h}.
// Iteration t (t = 0..T inclusive):
//   B) masked-retry spin on my 256-chunk of slot t&1 for tag t: each of the
//      4 loads predicated on its lane's !ok (monotonic tags => once matched,
//      the value is final for this step). First sweep full, later sweeps
//      touch only missing lines.
//   C) deposit into lh[t&1]; raw barrier (lgkmcnt only; vmem in flight)
//   D) hv = full h_{t-1} from LDS
//   E) [t<T] gates: chain init = pp[] (x-partials), 64 FMA vs reg-pinned
//      W_h, DPP reduce -> lane 63: acts, c, h, publish tag t+1
//   -- sched_barrier: nothing below may delay the publish --
//   X) [t+2<T] issue x[t+2] prefetch into xnN (read-only; earliest vmem
//      point => ~shadow+L of flight before the next spin drains it)
//   F) [t>0] y_{t-1} = out_w[u].hv (+DPP reduce), lane 63 stores out[t-1]
//   G) [t+1<T] pp[] = partials of W_x . x_{t+1} from xnP (retired long ago)
//   R) xnP <= xnN (register rotate)
// Skew safety (unchanged): every wave consumes the FULL h each step via its
// chunk + barrier; tag t+2 publish implies all waves passed poll t+1, so
// depth-2 slots never skip a tag. Publish stores are never vmcnt-drained
// in-loop; pollers enforce visibility.
// ---------------------------------------------------------------------------
__global__ __launch_bounds__(TPB, 1) void lstm_fused(
    const float* __restrict__ Ww,                 // [4096, 2048]
    const float* __restrict__ xg,                 // [T, 1024]
    const float* __restrict__ owm,                // [1024, 1024]
    const float* __restrict__ wb,                 // [4096]
    const float* __restrict__ obv,                // [1024]
    unsigned long long* __restrict__ hbuf,        // [2][1024] tagged
    float* __restrict__ out)                      // [T, 1024]
{
  __shared__ float whlds[16][HID];  // 64 KB: W_h rows m = ul*4+g
  __shared__ float wxlds[16][HID];  // 64 KB: W_x rows, same layout
  __shared__ float lh[2][HID];      // 8 KB: staged h, double-buffered

  const int tid = threadIdx.x;
  const int lane = tid & 63;
  const int wslot = tid >> 6;                 // 0..3 = unit-in-block
  const int u = blockIdx.x * UPB + wslot;     // this wave's hidden unit

  // Stage W_h and W_x rows for this block (float4, coalesced).
  {
    const float4* __restrict__ Ww4 = (const float4*)Ww;  // row stride 512 f4
    float4* wh4 = (float4*)&whlds[0][0];
    float4* wx4 = (float4*)&wxlds[0][0];
    for (int i = tid; i < 16 * 256; i += TPB) {
      const int m = i >> 8;            // 0..15
      const int e4 = i & 255;          // float4 index within row
      const int gg = m & 3;
      const int ul = m >> 2;
      const size_t row = (size_t)(gg * HID + blockIdx.x * UPB + ul) * 512;
      wh4[i] = Ww4[row + (IN_DIM / 4) + e4];   // recurrent half
      wx4[i] = Ww4[row + e4];                  // input half
    }
  }
  __syncthreads();

  const f32x4* wl4 = (const f32x4*)&whlds[wslot * 4][0];
  const f32x4* wxl = (const f32x4*)&wxlds[wslot * 4][0];

  // Hoist W_h fragments into registers for the whole loop (loop-invariant).
  f32x4 W[16];
#pragma unroll
  for (int r = 0; r < 4; ++r)
#pragma unroll
    for (int k = 0; k < 4; ++k)
      W[r * 4 + k] = wl4[r * 256 + k * 64 + lane];
#pragma unroll
  for (int i = 0; i < 16; ++i) asm volatile("" : "+v"(W[i]));

  // out_w row for this unit, pinned (16 VGPRs).
  f32x4 O[4];
  {
    const f32x4* ow4 = (const f32x4*)(owm + (size_t)u * HID);
#pragma unroll
    for (int k = 0; k < 4; ++k) O[k] = ow4[k * 64 + lane];
#pragma unroll
    for (int k = 0; k < 4; ++k) asm volatile("" : "+v"(O[k]));
  }

  const float bi = wb[u],           bf = wb[HID + u];
  const float bg = wb[2 * HID + u], bo = wb[3 * HID + u];
  const float oby = obv[u];

  // Prologue: x-partials for step 0, and xnP = x[1] for step 0's G.
  float pp[4];
  {
    const f32x4* xt4 = (const f32x4*)xg;
    f32x4 x0[4];
#pragma unroll
    for (int k = 0; k < 4; ++k) x0[k] = xt4[k * 64 + lane];
#pragma unroll
    for (int r = 0; r < 4; ++r) {
      float s = 0.0f;
#pragma unroll
      for (int k = 0; k < 4; ++k) {
        const f32x4 wx = wxl[r * 256 + k * 64 + lane];
        s = fmaf(wx.x, x0[k].x, s); s = fmaf(wx.y, x0[k].y, s);
        s = fmaf(wx.z, x0[k].z, s); s = fmaf(wx.w, x0[k].w, s);
      }
      pp[r] = s;
    }
  }
  f32x4 xnP[4];
  {
    const f32x4* xt4 = (const f32x4*)(xg + (size_t)1 * IN_DIM);
#pragma unroll
    for (int k = 0; k < 4; ++k) xnP[k] = xt4[k * 64 + lane];
  }

  float c = 0.0f;

  for (int t = 0; t <= T_STEPS; ++t) {
    // B) masked-retry spin: only lanes whose entry hasn't arrived re-issue
    // loads. Tags are monotonic; once matched, the u64 is final for step t.
    const unsigned long long* hs = hbuf + (size_t)(t & 1) * HID + wslot * 256;
    const unsigned want = (unsigned)t;
    unsigned long long p0 = 0, p1 = 0, p2 = 0, p3 = 0;
    bool ok0 = false, ok1 = false, ok2 = false, ok3 = false;
    for (;;) {
      if (!ok0) { p0 = PLOAD(hs + lane);       ok0 = ((unsigned)p0 == want); }
      if (!ok1) { p1 = PLOAD(hs + 64 + lane);  ok1 = ((unsigned)p1 == want); }
      if (!ok2) { p2 = PLOAD(hs + 128 + lane); ok2 = ((unsigned)p2 == want); }
      if (!ok3) { p3 = PLOAD(hs + 192 + lane); ok3 = ((unsigned)p3 == want); }
      if (__all((int)(ok0 & ok1 & ok2 & ok3))) break;
    }
    {
      float* dst = &lh[t & 1][wslot * 256];
      dst[lane]       = __uint_as_float((unsigned)(p0 >> 32));
      dst[64 + lane]  = __uint_as_float((unsigned)(p1 >> 32));
      dst[128 + lane] = __uint_as_float((unsigned)(p2 >> 32));
      dst[192 + lane] = __uint_as_float((unsigned)(p3 >> 32));
    }

    // C) raw barrier: drain LDS ops only; global loads/stores stay in flight
    asm volatile("s_waitcnt lgkmcnt(0)\n\ts_barrier" ::: "memory");

    // D) full h_{t-1} from LDS
    const f32x4* lhp = (const f32x4*)&lh[t & 1][0];
    f32x4 hv[4];
#pragma unroll
    for (int k = 0; k < 4; ++k) hv[k] = lhp[k * 64 + lane];

    // E) gates -> h_t -> publish (critical path; lane 63 is the publisher)
    if (t < T_STEPS) {
      float a[4];
#pragma unroll
      for (int r = 0; r < 4; ++r) {
        float s = pp[r];   // x-partial initializes the chain (summed by tree)
#pragma unroll
        for (int k = 0; k < 4; ++k) {
          s = fmaf(W[r*4+k].x, hv[k].x, s); s = fmaf(W[r*4+k].y, hv[k].y, s);
          s = fmaf(W[r*4+k].z, hv[k].z, s); s = fmaf(W[r*4+k].w, hv[k].w, s);
        }
        a[r] = wave_sum63(s);
      }
      // Only lane 63 holds real sums; other lanes compute garbage harmlessly.
      const float gi = a[0] + bi, gf = a[1] + bf, gc = a[2] + bg, go = a[3] + bo;
      const float si = sigf(gi), sf = sigf(gf), so = sigf(go);
      const float tg = fmaf(2.0f, sigf(2.0f * gc), -1.0f);   // tanh
      c = fmaf(sf, c, si * tg);
      const float h = so * fmaf(2.0f, sigf(2.0f * c), -1.0f);
      if (lane == 63) {
        const unsigned long long pk =
            ((unsigned long long)__float_as_uint(h) << 32) | (unsigned)(t + 1);
        __hip_atomic_store(hbuf + (size_t)((t + 1) & 1) * HID + u, pk,
                           __ATOMIC_RELAXED, __HIP_MEMORY_SCOPE_AGENT);
      }
    }

    // Nothing below may be scheduled above the publish.
    __builtin_amdgcn_sched_barrier(0);

    // X) x[t+2] prefetch: earliest vmem point after publish. Read-only
    // data -- no coherence pollution. Gets ~shadow + poll-L of flight
    // before the next spin's vmcnt(0) can drain it.
    f32x4 xnN[4];
    const bool pf = (t + 2 < T_STEPS);
    if (pf) {
      const f32x4* xt4 = (const f32x4*)(xg + (size_t)(t + 2) * IN_DIM);
#pragma unroll
      for (int k = 0; k < 4; ++k) xnN[k] = xt4[k * 64 + lane];
    }

    // F) y_{t-1} = out_w[u] . h_{t-1} + out_b[u]; store also has a full
    // shadow+spin to retire before the next drain.
    if (t > 0) {
      float yv = 0.0f;
#pragma unroll
      for (int k = 0; k < 4; ++k) {
        yv = fmaf(O[k].x, hv[k].x, yv); yv = fmaf(O[k].y, hv[k].y, yv);
        yv = fmaf(O[k].z, hv[k].z, yv); yv = fmaf(O[k].w, hv[k].w, yv);
      }
      yv = wave_sum63(yv);
      if (lane == 63) out[(size_t)(t - 1) * OUT_DIM + u] = yv + oby;
    }
    __builtin_amdgcn_sched_barrier(0);

    // G) x-partials for step t+1 from xnP (issued a full step ago --
    // retired by this iteration's spin drain; never stalls).
    if (t + 1 < T_STEPS) {
#pragma unroll
      for (int r = 0; r < 4; ++r) {
        float s = 0.0f;
#pragma unroll
        for (int k = 0; k < 4; ++k) {
          const f32x4 wx = wxl[r * 256 + k * 64 + lane];
          s = fmaf(wx.x, xnP[k].x, s); s = fmaf(wx.y, xnP[k].y, s);
          s = fmaf(wx.z, xnP[k].z, s); s = fmaf(wx.w, xnP[k].w, s);
        }
        pp[r] = s;
      }
    }

    // R) rotate the x double-buffer (16 v_mov in the shadow).
    if (pf) {
#pragma unroll
      for (int k = 0; k < 4; ++k) xnP[k] = xnN[k];
    }
  }
}

// ---------------------------------------------------------------------------
// Workspace layout (bytes): [0, 16K) : hbuf[2][1024] tagged u64 (memset 0)
// ---------------------------------------------------------------------------
extern "C" void kernel_launch(void* const* d_in, const int* in_sizes, int n_in,
                              void* d_out, int out_size, void* d_ws, size_t ws_size,
                              hipStream_t stream) {
  (void)in_sizes; (void)n_in; (void)out_size; (void)ws_size;

  const float* x     = (const float*)d_in[0];  // [T,1,IN]
  const float* W_w   = (const float*)d_in[1];  // [4096, 2048]
  const float* W_b   = (const float*)d_in[2];  // [4096]
  const float* out_w = (const float*)d_in[3];  // [1024, 1024]
  const float* out_b = (const float*)d_in[4];  // [1024]
  float* out = (float*)d_out;                  // [T,1,1024]

  unsigned long long* hbuf = (unsigned long long*)d_ws;
  hipMemsetAsync(d_ws, 0, 16384, stream);

  lstm_fused<<<NBLK, TPB, 0, stream>>>(W_w, x, out_w, W_b, out_b, hbuf, out);
}

// Round 6
// 13366.956 us; speedup vs baseline: 1.3684x; 1.3684x over previous
//
#include <hip/hip_runtime.h>
#include <cstdint>
#include <cstddef>

// Problem constants
#define T_STEPS 8192
#define IN_DIM  1024
#define HID     1024
#define OUT_DIM 1024
#define G4      4096   // 4*HID

// R14: geometry change, spin inner structure UNTOUCHED (R10/R13 lesson:
// uniform loads + single drain + __all is load-bearing).
//   128 blocks x 512 threads (8 waves), 8 units/block, 1 block/CU.
//   - poll fan-in per hbuf line: 256 -> 128 concurrent reader blocks,
//     and each line now has exactly ONE producer block (u=bid*8..+7 fill
//     one 64B line) -> one ownership transition per line per step.
//   - chunk/wave = 128 entries -> 2 uniform loads per sweep (was 4).
//   - 2 waves/SIMD -> shadow/compute issue from co-resident waves overlaps.
//   Fit: W_h loaded global->regs directly (no LDS staging); W_x stays in
//   LDS (8 units x 16KB = 128KB) + lh 8KB = 136KB; launch_bounds(512,2)
//   caps VGPR at 256 (est ~190). Protocol/tags/barrier identical to R12.
#define NBLK 128
#define TPB  512
#define UPB  8    // units per block (1 per wave)

typedef __attribute__((ext_vector_type(4))) float f32x4;

#define PLOAD(p) __hip_atomic_load((p), __ATOMIC_RELAXED, __HIP_MEMORY_SCOPE_AGENT)

__device__ __forceinline__ float sigf(float x) {
  return 1.0f / (1.0f + __expf(-x));
}

template<int CTRL>
__device__ __forceinline__ float dpp_add(float v) {
  int p = __builtin_amdgcn_update_dpp(0, __float_as_int(v), CTRL, 0xf, 0xf, true);
  return v + __int_as_float(p);
}

// Full 64-lane sum, all-VALU (DPP). Result valid in LANE 63 only.
__device__ __forceinline__ float wave_sum63(float v) {
  v = dpp_add<0xB1>(v);    // quad_perm [1,0,3,2]
  v = dpp_add<0x4E>(v);    // quad_perm [2,3,0,1]
  v = dpp_add<0x141>(v);   // row_half_mirror
  v = dpp_add<0x140>(v);   // row_mirror
  v = dpp_add<0x142>(v);   // row_bcast15
  v = dpp_add<0x143>(v);   // row_bcast31
  return v;
}

// ---------------------------------------------------------------------------
// Fused persistent LSTM: tagged dataflow, hbuf: [2][1024] u64 {lo=tag,hi=h}.
// Iteration t (t = 0..T inclusive):
//   B) spin on my 128-chunk of slot t&1 for tag t (2 uniform loads, single
//      drain, __all -- R12's shape, shorter)
//   C) deposit into lh[t&1]; raw barrier (lgkmcnt only; vmem in flight)
//   D) hv = full h_{t-1} from LDS
//   E) [t<T] gates: chain init = pp[], 64 FMA vs reg-pinned W_h, DPP
//      reduce -> lane 63: acts, c, h, publish tag t+1
//   -- sched_barrier: nothing below may delay the publish --
//   X) [t+2<T] issue x[t+2] prefetch into xnN (double-buffered so the next
//      spin's vmcnt(0) drain is ~free -- R12's gain)
//   F) [t>0] y_{t-1} = out_w[u].hv (+DPP reduce), lane 63 stores out[t-1]
//   G) [t+1<T] pp[] = partials of W_x . x_{t+1} from xnP (retired long ago)
//   R) xnP <= xnN (register rotate)
// Skew safety (block-count independent): a block publishes tag t+2 into
// slot s=t&1 only after its barrier C(t+1); passing poll t+1 requires every
// block to have published t+1, which requires their barrier C(t), i.e. all
// consumers finished reading tag t from slot s. Depth-2 never skips a tag.
// ---------------------------------------------------------------------------
__global__ __launch_bounds__(TPB, 2) void lstm_fused(
    const float* __restrict__ Ww,                 // [4096, 2048]
    const float* __restrict__ xg,                 // [T, 1024]
    const float* __restrict__ owm,                // [1024, 1024]
    const float* __restrict__ wb,                 // [4096]
    const float* __restrict__ obv,                // [1024]
    unsigned long long* __restrict__ hbuf,        // [2][1024] tagged
    float* __restrict__ out)                      // [T, 1024]
{
  __shared__ float wxlds[32][HID];  // 128 KB: W_x rows m = ul*4+g, ul=0..7
  __shared__ float lh[2][HID];      // 8 KB: staged h, double-buffered

  const int tid = threadIdx.x;
  const int lane = tid & 63;
  const int wslot = tid >> 6;                 // 0..7 = unit-in-block
  const int u = blockIdx.x * UPB + wslot;     // this wave's hidden unit

  // Stage W_x rows for this block into LDS (float4, coalesced).
  {
    const float4* __restrict__ Ww4 = (const float4*)Ww;  // row stride 512 f4
    float4* wx4 = (float4*)&wxlds[0][0];
    for (int i = tid; i < 32 * 256; i += TPB) {
      const int m = i >> 8;            // 0..31
      const int e4 = i & 255;          // float4 index within x-half
      const int gg = m & 3;
      const int ul = m >> 2;
      const size_t row = (size_t)(gg * HID + blockIdx.x * UPB + ul) * 512;
      wx4[i] = Ww4[row + e4];                  // input half
    }
  }

  // W_h fragments: global -> registers directly (coalesced 16B/lane).
  f32x4 W[16];
  {
    const f32x4* WwG = (const f32x4*)Ww;
#pragma unroll
    for (int r = 0; r < 4; ++r)
#pragma unroll
      for (int k = 0; k < 4; ++k)
        W[r * 4 + k] = WwG[(size_t)(r * HID + u) * 512 + 256 + k * 64 + lane];
#pragma unroll
    for (int i = 0; i < 16; ++i) asm volatile("" : "+v"(W[i]));
  }

  // out_w row for this unit, pinned (16 VGPRs).
  f32x4 O[4];
  {
    const f32x4* ow4 = (const f32x4*)(owm + (size_t)u * HID);
#pragma unroll
    for (int k = 0; k < 4; ++k) O[k] = ow4[k * 64 + lane];
#pragma unroll
    for (int k = 0; k < 4; ++k) asm volatile("" : "+v"(O[k]));
  }

  const float bi = wb[u],           bf = wb[HID + u];
  const float bg = wb[2 * HID + u], bo = wb[3 * HID + u];
  const float oby = obv[u];

  __syncthreads();   // wxlds ready before prologue pp

  const f32x4* wxl = (const f32x4*)&wxlds[wslot * 4][0];

  // Prologue: x-partials for step 0, and xnP = x[1] for step 0's G.
  float pp[4];
  {
    const f32x4* xt4 = (const f32x4*)xg;
    f32x4 x0[4];
#pragma unroll
    for (int k = 0; k < 4; ++k) x0[k] = xt4[k * 64 + lane];
#pragma unroll
    for (int r = 0; r < 4; ++r) {
      float s = 0.0f;
#pragma unroll
      for (int k = 0; k < 4; ++k) {
        const f32x4 wx = wxl[r * 256 + k * 64 + lane];
        s = fmaf(wx.x, x0[k].x, s); s = fmaf(wx.y, x0[k].y, s);
        s = fmaf(wx.z, x0[k].z, s); s = fmaf(wx.w, x0[k].w, s);
      }
      pp[r] = s;
    }
  }
  f32x4 xnP[4];
  {
    const f32x4* xt4 = (const f32x4*)(xg + (size_t)1 * IN_DIM);
#pragma unroll
    for (int k = 0; k < 4; ++k) xnP[k] = xt4[k * 64 + lane];
  }

  float c = 0.0f;

  for (int t = 0; t <= T_STEPS; ++t) {
    // B) spin: 2 uniform loads, single drain, __all (R12 shape, halved).
    const unsigned long long* hs = hbuf + (size_t)(t & 1) * HID + wslot * 128;
    const unsigned want = (unsigned)t;
    unsigned long long p0, p1;
    for (;;) {
      p0 = PLOAD(hs + lane);
      p1 = PLOAD(hs + 64 + lane);
      bool ok = ((unsigned)p0 == want) & ((unsigned)p1 == want);
      if (__all((int)ok)) break;
    }
    {
      float* dst = &lh[t & 1][wslot * 128];
      dst[lane]      = __uint_as_float((unsigned)(p0 >> 32));
      dst[64 + lane] = __uint_as_float((unsigned)(p1 >> 32));
    }

    // C) raw barrier: drain LDS ops only; global loads/stores stay in flight
    asm volatile("s_waitcnt lgkmcnt(0)\n\ts_barrier" ::: "memory");

    // D) full h_{t-1} from LDS
    const f32x4* lhp = (const f32x4*)&lh[t & 1][0];
    f32x4 hv[4];
#pragma unroll
    for (int k = 0; k < 4; ++k) hv[k] = lhp[k * 64 + lane];

    // E) gates -> h_t -> publish (critical path; lane 63 is the publisher)
    if (t < T_STEPS) {
      float a[4];
#pragma unroll
      for (int r = 0; r < 4; ++r) {
        float s = pp[r];   // x-partial initializes the chain (summed by tree)
#pragma unroll
        for (int k = 0; k < 4; ++k) {
          s = fmaf(W[r*4+k].x, hv[k].x, s); s = fmaf(W[r*4+k].y, hv[k].y, s);
          s = fmaf(W[r*4+k].z, hv[k].z, s); s = fmaf(W[r*4+k].w, hv[k].w, s);
        }
        a[r] = wave_sum63(s);
      }
      // Only lane 63 holds real sums; other lanes compute garbage harmlessly.
      const float gi = a[0] + bi, gf = a[1] + bf, gc = a[2] + bg, go = a[3] + bo;
      const float si = sigf(gi), sf = sigf(gf), so = sigf(go);
      const float tg = fmaf(2.0f, sigf(2.0f * gc), -1.0f);   // tanh
      c = fmaf(sf, c, si * tg);
      const float h = so * fmaf(2.0f, sigf(2.0f * c), -1.0f);
      if (lane == 63) {
        const unsigned long long pk =
            ((unsigned long long)__float_as_uint(h) << 32) | (unsigned)(t + 1);
        __hip_atomic_store(hbuf + (size_t)((t + 1) & 1) * HID + u, pk,
                           __ATOMIC_RELAXED, __HIP_MEMORY_SCOPE_AGENT);
      }
    }

    // Nothing below may be scheduled above the publish.
    __builtin_amdgcn_sched_barrier(0);

    // X) x[t+2] prefetch: earliest vmem point after publish; retires during
    // the next spin, so its drain is ~free (R12's gain, kept).
    f32x4 xnN[4];
    const bool pf = (t + 2 < T_STEPS);
    if (pf) {
      const f32x4* xt4 = (const f32x4*)(xg + (size_t)(t + 2) * IN_DIM);
#pragma unroll
      for (int k = 0; k < 4; ++k) xnN[k] = xt4[k * 64 + lane];
    }

    // F) y_{t-1} = out_w[u] . h_{t-1} + out_b[u]  (shadow work)
    if (t > 0) {
      float yv = 0.0f;
#pragma unroll
      for (int k = 0; k < 4; ++k) {
        yv = fmaf(O[k].x, hv[k].x, yv); yv = fmaf(O[k].y, hv[k].y, yv);
        yv = fmaf(O[k].z, hv[k].z, yv); yv = fmaf(O[k].w, hv[k].w, yv);
      }
      yv = wave_sum63(yv);
      if (lane == 63) out[(size_t)(t - 1) * OUT_DIM + u] = yv + oby;
    }
    __builtin_amdgcn_sched_barrier(0);

    // G) x-partials for step t+1 from xnP (issued a full step ago --
    // retired by this iteration's spin drain; never stalls).
    if (t + 1 < T_STEPS) {
#pragma unroll
      for (int r = 0; r < 4; ++r) {
        float s = 0.0f;
#pragma unroll
        for (int k = 0; k < 4; ++k) {
          const f32x4 wx = wxl[r * 256 + k * 64 + lane];
          s = fmaf(wx.x, xnP[k].x, s); s = fmaf(wx.y, xnP[k].y, s);
          s = fmaf(wx.z, xnP[k].z, s); s = fmaf(wx.w, xnP[k].w, s);
        }
        pp[r] = s;
      }
    }

    // R) rotate the x double-buffer (16 v_mov in the shadow).
    if (pf) {
#pragma unroll
      for (int k = 0; k < 4; ++k) xnP[k] = xnN[k];
    }
  }
}

// ---------------------------------------------------------------------------
// Workspace layout (bytes): [0, 16K) : hbuf[2][1024] tagged u64 (memset 0)
// ---------------------------------------------------------------------------
extern "C" void kernel_launch(void* const* d_in, const int* in_sizes, int n_in,
                              void* d_out, int out_size, void* d_ws, size_t ws_size,
                              hipStream_t stream) {
  (void)in_sizes; (void)n_in; (void)out_size; (void)ws_size;

  const float* x     = (const float*)d_in[0];  // [T,1,IN]
  const float* W_w   = (const float*)d_in[1];  // [4096, 2048]
  const float* W_b   = (const float*)d_in[2];  // [4096]
  const float* out_w = (const float*)d_in[3];  // [1024, 1024]
  const float* out_b = (const float*)d_in[4];  // [1024]
  float* out = (float*)d_out;                  // [T,1,1024]

  unsigned long long* hbuf = (unsigned long long*)d_ws;
  hipMemsetAsync(d_ws, 0, 16384, stream);

  lstm_fused<<<NBLK, TPB, 0, stream>>>(W_w, x, out_w, W_b, out_b, hbuf, out);
}